// Round 2
// baseline (1018.897 us; speedup 1.0000x reference)
//
#include <hip/hip_runtime.h>

// ---------------------------------------------------------------------------
// ColumnParallelLinearWithTopping: out = x @ W_base^T + x[t] @ (DeltaW[j] + A[j]B[j])
// T=8192, D_IN=D_OUT=4096, N_ADAPT=8, RANK=16, fp32 in/out.
// W_tot[j][o][i] = W_base[o][i] + DeltaW[j][i][o] + sum_r A[j][i][r]B[j][r][o] (bf16),
// then ONE grouped GEMM (tokens grouped by adapter).
// ws_size-ADAPTIVE: processes npp adapters per pass so workspace never overflows.
// ---------------------------------------------------------------------------

#define T_TOKENS 8192
#define DIM 4096
#define NADAPT 8
#define RANK 16
#define BM 128
#define BN 128
#define BK 64
#define MAX_TILES 72

typedef __attribute__((ext_vector_type(8))) short bf16x8;
typedef __attribute__((ext_vector_type(4))) float f32x4;

__device__ __forceinline__ unsigned short f2bf(float f) {
  union { float f; unsigned u; } v; v.f = f;
  unsigned r = v.u + 0x7FFFu + ((v.u >> 16) & 1u);   // RNE
  return (unsigned short)(r >> 16);
}

__device__ __forceinline__ void gload_lds16(const void* g, void* l) {
  __builtin_amdgcn_global_load_lds(
      (const __attribute__((address_space(1))) void*)g,
      (__attribute__((address_space(3))) void*)l, 16, 0, 0);
}

// ---------------------------------------------------------------------------
// Kernel 1: group tokens by adapter (stable compaction), build tile descriptors.
// meta layout: [0..7]=counts, [8..16]=padded offsets, [17]=ntiles,
//              [32+3*t .. ] = {adapter, perm_base, rows}
// ---------------------------------------------------------------------------
__global__ void prep_kernel(const int* __restrict__ idx, int* __restrict__ perm,
                            int* __restrict__ meta) {
  __shared__ int s_cnt[NADAPT];
  __shared__ int s_padoff[NADAPT + 1];
  __shared__ int s_wsum[16];
  const int tid = threadIdx.x;
  const int lane = tid & 63;
  const int wave = tid >> 6;

  if (tid < NADAPT) s_cnt[tid] = 0;
  __syncthreads();
  for (int t = tid; t < T_TOKENS; t += 1024) atomicAdd(&s_cnt[idx[t]], 1);
  __syncthreads();

  if (tid == 0) {
    int off = 0, nt = 0;
    for (int j = 0; j < NADAPT; ++j) {
      meta[j] = s_cnt[j];
      s_padoff[j] = off;
      const int c = s_cnt[j];
      const int ntj = (c + BM - 1) / BM;
      for (int i = 0; i < ntj; ++i) {
        meta[32 + 3 * nt + 0] = j;
        meta[32 + 3 * nt + 1] = off + i * BM;
        meta[32 + 3 * nt + 2] = min(BM, c - i * BM);
        ++nt;
      }
      off += ntj * BM;
    }
    s_padoff[NADAPT] = off;
    meta[17] = nt;
    for (int j = 0; j <= NADAPT; ++j) meta[8 + j] = s_padoff[j];
  }
  __syncthreads();

  const int total_pad = s_padoff[NADAPT];
  for (int t = tid; t < total_pad; t += 1024) perm[t] = -1;
  __syncthreads();

  // stable per-adapter compaction via ballot prefix sums
  for (int j = 0; j < NADAPT; ++j) {
    int base = s_padoff[j];
    for (int c0 = 0; c0 < T_TOKENS; c0 += 1024) {
      const int t = c0 + tid;
      const int flag = (idx[t] == j) ? 1 : 0;
      const unsigned long long bal = __ballot(flag);
      const int wpos = __popcll(bal & ((1ULL << lane) - 1ULL));
      if (lane == 0) s_wsum[wave] = __popcll(bal);
      __syncthreads();
      int woff = 0, ctot = 0;
      for (int w = 0; w < 16; ++w) {
        const int v = s_wsum[w];
        if (w < wave) woff += v;
        ctot += v;
      }
      if (flag) perm[base + woff + wpos] = t;
      base += ctot;
      __syncthreads();
    }
  }
}

// ---------------------------------------------------------------------------
// Kernel 2: x fp32 -> bf16, vectorized. One thread = 8 elements.
// ---------------------------------------------------------------------------
__global__ void convert_x_kernel(const float* __restrict__ x,
                                 unsigned short* __restrict__ xb) {
  const long long i = (long long)blockIdx.x * 256 + threadIdx.x;
  const float4* x4 = (const float4*)x;
  const float4 a = x4[2 * i];
  const float4 b = x4[2 * i + 1];
  uint4 o;
  o.x = (unsigned)f2bf(a.x) | ((unsigned)f2bf(a.y) << 16);
  o.y = (unsigned)f2bf(a.z) | ((unsigned)f2bf(a.w) << 16);
  o.z = (unsigned)f2bf(b.x) | ((unsigned)f2bf(b.y) << 16);
  o.w = (unsigned)f2bf(b.z) | ((unsigned)f2bf(b.w) << 16);
  ((uint4*)xb)[i] = o;
}

// ---------------------------------------------------------------------------
// Kernel 3: W_tot[jj][o][i] = Wb[o][i] + DW[j0+jj][i][o] + sum_r A[i][r]B[r][o]
// 64x64 tile per block; DeltaW transposed through padded LDS.
// ---------------------------------------------------------------------------
__global__ __launch_bounds__(256) void build_wtot_kernel(
    const float* __restrict__ Wb, const float* __restrict__ Am,
    const float* __restrict__ Bm, const float* __restrict__ DW,
    unsigned short* __restrict__ Wt, int j0) {
  const int jj = blockIdx.z;
  const int j = j0 + jj;
  const int i0 = blockIdx.x << 6;
  const int o0 = blockIdx.y << 6;
  __shared__ float Dl[64][67];   // [i][o]
  __shared__ float Al[64][17];   // [i][r]
  __shared__ float Bl[16][64];   // [r][o]
  const int tid = threadIdx.x;

  const float* dwp = DW + ((size_t)j * DIM + i0) * DIM + o0;
#pragma unroll
  for (int q = 0; q < 4; ++q) {
    const int lin = q * 256 + tid;
    const int i = lin >> 4;
    const int o4 = (lin & 15) << 2;
    const float4 v = *(const float4*)(dwp + (size_t)i * DIM + o4);
    Dl[i][o4] = v.x; Dl[i][o4 + 1] = v.y; Dl[i][o4 + 2] = v.z; Dl[i][o4 + 3] = v.w;
  }
  {
    const int ai = tid >> 2, r4 = (tid & 3) << 2;
    const float4 v = *(const float4*)(Am + ((size_t)j * DIM + i0 + ai) * RANK + r4);
    Al[ai][r4] = v.x; Al[ai][r4 + 1] = v.y; Al[ai][r4 + 2] = v.z; Al[ai][r4 + 3] = v.w;
  }
  {
    const int br = tid >> 4, bo4 = (tid & 15) << 2;
    const float4 v = *(const float4*)(Bm + ((size_t)j * RANK + br) * DIM + o0 + bo4);
    Bl[br][bo4] = v.x; Bl[br][bo4 + 1] = v.y; Bl[br][bo4 + 2] = v.z; Bl[br][bo4 + 3] = v.w;
  }
  __syncthreads();

  const int oo = tid >> 5;         // 0..7
  const int i2 = (tid & 31) << 1;  // even 0..62
#pragma unroll
  for (int p = 0; p < 8; ++p) {
    const int o = p * 8 + oo;
    const int og = o0 + o;
    const float2 wb = *(const float2*)(Wb + (size_t)og * DIM + i0 + i2);
    float s0 = wb.x + Dl[i2][o];
    float s1 = wb.y + Dl[i2 + 1][o];
#pragma unroll
    for (int r = 0; r < RANK; ++r) {
      const float bro = Bl[r][o];
      s0 += Al[i2][r] * bro;
      s1 += Al[i2 + 1][r] * bro;
    }
    const unsigned pk = (unsigned)f2bf(s0) | ((unsigned)f2bf(s1) << 16);
    *(unsigned*)(Wt + ((size_t)jj * DIM + og) * DIM + i0 + i2) = pk;
  }
}

// ---------------------------------------------------------------------------
// Kernel 4: grouped GEMM. 128x128x64 tile, 4 waves (2x2), 16x16x32 bf16 MFMA.
// Only tiles with adapter in [j0, j0+npp) run; Wt holds that adapter chunk.
// USE_XB: A staged via global_load_lds from pre-converted bf16 x.
// else:   A staged from fp32 x with in-register conversion + ds_write.
// ---------------------------------------------------------------------------
template <bool USE_XB>
__global__ __launch_bounds__(256) void gemm_kernel(
    const unsigned short* __restrict__ xb, const float* __restrict__ xf,
    const unsigned short* __restrict__ Wt,
    const int* __restrict__ perm, const int* __restrict__ meta,
    float* __restrict__ out, int j0, int npp) {
  const int ntiles = meta[17];
  const int mt = blockIdx.x;
  if (mt >= ntiles) return;
  const int adapter = meta[32 + 3 * mt];
  if (adapter < j0 || adapter >= j0 + npp) return;
  const int slot = adapter - j0;
  const int nt = blockIdx.y;
  const int pbase = meta[32 + 3 * mt + 1];
  const int nbase = nt << 7;

  __shared__ __align__(16) unsigned short As[BM * BK];
  __shared__ __align__(16) unsigned short Bs[BN * BK];

  const int tid = threadIdx.x;
  const int lane = tid & 63;
  const int wave = tid >> 6;

  const unsigned short* aSrcB[4];
  const float* aSrcF[4];
  const unsigned short* bSrc[4];
  unsigned short* aDst[4];
  unsigned short* bDst[4];
#pragma unroll
  for (int q = 0; q < 4; ++q) {
    const int c = wave * 4 + q;        // chunk 0..15 (1 KiB each)
    const int r = c * 8 + (lane >> 3); // tile row 0..127
    int pr = perm[pbase + r];
    if (pr < 0) pr = 0;                // padded row: load row 0, never stored
    if (USE_XB) aSrcB[q] = xb + (size_t)pr * DIM + (lane & 7) * 8;
    else        aSrcF[q] = xf + (size_t)pr * DIM + (lane & 7) * 8;
    bSrc[q] = Wt + ((size_t)slot * DIM + nbase + r) * DIM + (lane & 7) * 8;
    aDst[q] = As + c * 512;
    bDst[q] = Bs + c * 512;
  }

  const int wr = wave >> 1, wc = wave & 1;
  const int fr = lane & 15, kg = lane >> 4;

  const f32x4 zero = {0.f, 0.f, 0.f, 0.f};
  f32x4 acc[4][4];
#pragma unroll
  for (int m = 0; m < 4; ++m)
#pragma unroll
    for (int n = 0; n < 4; ++n) acc[m][n] = zero;

  for (int k0 = 0; k0 < DIM; k0 += BK) {
    if (USE_XB) {
#pragma unroll
      for (int q = 0; q < 4; ++q) gload_lds16(aSrcB[q] + k0, aDst[q]);
    } else {
#pragma unroll
      for (int q = 0; q < 4; ++q) {
        const float4 va = *(const float4*)(aSrcF[q] + k0);
        const float4 vb = *(const float4*)(aSrcF[q] + k0 + 4);
        union { bf16x8 v; unsigned short s[8]; } u;
        u.s[0] = f2bf(va.x); u.s[1] = f2bf(va.y); u.s[2] = f2bf(va.z); u.s[3] = f2bf(va.w);
        u.s[4] = f2bf(vb.x); u.s[5] = f2bf(vb.y); u.s[6] = f2bf(vb.z); u.s[7] = f2bf(vb.w);
        *(bf16x8*)(aDst[q] + lane * 8) = u.v;
      }
    }
#pragma unroll
    for (int q = 0; q < 4; ++q) gload_lds16(bSrc[q] + k0, bDst[q]);
    __syncthreads();
#pragma unroll
    for (int kk = 0; kk < 2; ++kk) {
      bf16x8 a[4], b[4];
#pragma unroll
      for (int m = 0; m < 4; ++m)
        a[m] = *(const bf16x8*)(&As[(wr * 64 + m * 16 + fr) * BK + kk * 32 + kg * 8]);
#pragma unroll
      for (int n = 0; n < 4; ++n)
        b[n] = *(const bf16x8*)(&Bs[(wc * 64 + n * 16 + fr) * BK + kk * 32 + kg * 8]);
#pragma unroll
      for (int m = 0; m < 4; ++m)
#pragma unroll
        for (int n = 0; n < 4; ++n)
          acc[m][n] = __builtin_amdgcn_mfma_f32_16x16x32_bf16(a[m], b[n], acc[m][n], 0, 0, 0);
    }
    __syncthreads();
  }

  // epilogue: C/D map col=lane&15, row=(lane>>4)*4+reg (m89-verified)
#pragma unroll
  for (int m = 0; m < 4; ++m) {
#pragma unroll
    for (int t = 0; t < 4; ++t) {
      const int rt = wr * 64 + m * 16 + kg * 4 + t;
      const int pr = perm[pbase + rt];
      if (pr < 0) continue;
      float* orow = out + (size_t)pr * DIM + nbase + wc * 64;
#pragma unroll
      for (int n = 0; n < 4; ++n) orow[n * 16 + fr] = acc[m][n][t];
    }
  }
}

// ---------------------------------------------------------------------------
extern "C" void kernel_launch(void* const* d_in, const int* in_sizes, int n_in,
                              void* d_out, int out_size, void* d_ws, size_t ws_size,
                              hipStream_t stream) {
  const float* x  = (const float*)d_in[0];
  const int* widx = (const int*)d_in[1];
  const float* Wb = (const float*)d_in[2];
  const float* Am = (const float*)d_in[3];
  const float* Bm = (const float*)d_in[4];
  const float* DW = (const float*)d_in[5];
  float* out = (float*)d_out;

  const size_t XB_BYTES = (size_t)T_TOKENS * DIM * 2;       // 64 MiB
  const size_t WT1_BYTES = (size_t)DIM * DIM * 2;           // 32 MiB / adapter
  const size_t PM_BYTES = 16384 * sizeof(int) + 4096;       // perm + meta

  // pick the largest adapters-per-pass that fits ws_size (host-side, constant)
  int npp = 0;
  bool use_xb = true;
  for (int cand = NADAPT; cand >= 1; cand >>= 1) {
    if (XB_BYTES + (size_t)cand * WT1_BYTES + PM_BYTES <= ws_size) { npp = cand; break; }
  }
  if (npp == 0) { npp = 1; use_xb = false; }  // floor tier: ~32.1 MiB

  char* ws = (char*)d_ws;
  unsigned short* xb = (unsigned short*)ws;  // only if use_xb
  unsigned short* Wt = (unsigned short*)(ws + (use_xb ? XB_BYTES : 0));
  char* tail = (char*)Wt + (size_t)npp * WT1_BYTES;
  int* perm = (int*)tail;
  int* meta = (int*)(tail + 16384 * sizeof(int));

  prep_kernel<<<dim3(1), dim3(1024), 0, stream>>>(widx, perm, meta);
  if (use_xb)
    convert_x_kernel<<<dim3(T_TOKENS * DIM / (256 * 8)), dim3(256), 0, stream>>>(x, xb);

  const int passes = NADAPT / npp;
  for (int p = 0; p < passes; ++p) {
    const int j0 = p * npp;
    build_wtot_kernel<<<dim3(DIM / 64, DIM / 64, npp), dim3(256), 0, stream>>>(
        Wb, Am, Bm, DW, Wt, j0);
    if (use_xb)
      gemm_kernel<true><<<dim3(MAX_TILES, DIM / BN), dim3(256), 0, stream>>>(
          xb, nullptr, Wt, perm, meta, out, j0, npp);
    else
      gemm_kernel<false><<<dim3(MAX_TILES, DIM / BN), dim3(256), 0, stream>>>(
          nullptr, x, Wt, perm, meta, out, j0, npp);
  }
}

// Round 3
// 885.225 us; speedup vs baseline: 1.1510x; 1.1510x over previous
//
#include <hip/hip_runtime.h>

// ---------------------------------------------------------------------------
// out = x @ W_base^T + x[t] @ (DeltaW[j] + A[j]B[j]);  T=8192, D=4096, J=8, R=16.
// W_tot[j][o][i] = Wb[o][i] + DW[j][i][o] + (A@B)[i][o]  (bf16, [N][K] layout),
// then ONE grouped GEMM.  GEMM = 256x256x64 8-phase schedule (T1+T2+T3+T4+T5).
// ---------------------------------------------------------------------------

#define T_TOKENS 8192
#define DIM 4096
#define NADAPT 8
#define RANK 16

// 8-phase GEMM geometry
#define BM2 256
#define BN2 256
#define MAXT2 40
#define GRIDX2 (MAXT2 * 16)   // 640, %8==0

// fallback 2-phase geometry
#define BM1 128
#define MAXT1 72

typedef __attribute__((ext_vector_type(8))) short bf16x8;
typedef __attribute__((ext_vector_type(4))) float f32x4;

__device__ __forceinline__ unsigned short f2bf(float f) {
  union { float f; unsigned u; } v; v.f = f;
  unsigned r = v.u + 0x7FFFu + ((v.u >> 16) & 1u);   // RNE
  return (unsigned short)(r >> 16);
}

__device__ __forceinline__ void gload_lds16(const void* g, void* l) {
  __builtin_amdgcn_global_load_lds(
      (const __attribute__((address_space(1))) void*)g,
      (__attribute__((address_space(3))) void*)l, 16, 0, 0);
}

template <int N> __device__ __forceinline__ void vmwait() {
  if constexpr (N == 0)       asm volatile("s_waitcnt vmcnt(0)" ::: "memory");
  else if constexpr (N == 4)  asm volatile("s_waitcnt vmcnt(4)" ::: "memory");
  else if constexpr (N == 8)  asm volatile("s_waitcnt vmcnt(8)" ::: "memory");
  else                        asm volatile("s_waitcnt vmcnt(10)" ::: "memory");
}

// ---------------------------------------------------------------------------
// Kernel 1: group tokens by adapter (stable compaction), tile descriptors.
// meta: [0..7]=counts, [8..16]=padded offsets, [17]=ntiles, [32+3t..]={adapter,pbase,rows}
// ---------------------------------------------------------------------------
__global__ void prep_kernel(const int* __restrict__ idx, int* __restrict__ perm,
                            int* __restrict__ meta, int padm) {
  __shared__ int s_cnt[NADAPT];
  __shared__ int s_padoff[NADAPT + 1];
  __shared__ int s_wsum[16];
  const int tid = threadIdx.x;
  const int lane = tid & 63;
  const int wave = tid >> 6;

  if (tid < NADAPT) s_cnt[tid] = 0;
  __syncthreads();
  for (int t = tid; t < T_TOKENS; t += 1024) atomicAdd(&s_cnt[idx[t]], 1);
  __syncthreads();

  if (tid == 0) {
    int off = 0, nt = 0;
    for (int j = 0; j < NADAPT; ++j) {
      meta[j] = s_cnt[j];
      s_padoff[j] = off;
      const int c = s_cnt[j];
      const int ntj = (c + padm - 1) / padm;
      for (int i = 0; i < ntj; ++i) {
        meta[32 + 3 * nt + 0] = j;
        meta[32 + 3 * nt + 1] = off + i * padm;
        meta[32 + 3 * nt + 2] = min(padm, c - i * padm);
        ++nt;
      }
      off += ntj * padm;
    }
    s_padoff[NADAPT] = off;
    meta[17] = nt;
    for (int j = 0; j <= NADAPT; ++j) meta[8 + j] = s_padoff[j];
  }
  __syncthreads();

  const int total_pad = s_padoff[NADAPT];
  for (int t = tid; t < total_pad; t += 1024) perm[t] = -1;
  __syncthreads();

  for (int j = 0; j < NADAPT; ++j) {
    int base = s_padoff[j];
    for (int c0 = 0; c0 < T_TOKENS; c0 += 1024) {
      const int t = c0 + tid;
      const int flag = (idx[t] == j) ? 1 : 0;
      const unsigned long long bal = __ballot(flag);
      const int wpos = __popcll(bal & ((1ULL << lane) - 1ULL));
      if (lane == 0) s_wsum[wave] = __popcll(bal);
      __syncthreads();
      int woff = 0, ctot = 0;
      for (int w = 0; w < 16; ++w) {
        const int v = s_wsum[w];
        if (w < wave) woff += v;
        ctot += v;
      }
      if (flag) perm[base + woff + wpos] = t;
      base += ctot;
      __syncthreads();
    }
  }
}

// ---------------------------------------------------------------------------
// Kernel 2: x fp32 -> bf16, vectorized.
// ---------------------------------------------------------------------------
__global__ void convert_x_kernel(const float* __restrict__ x,
                                 unsigned short* __restrict__ xb) {
  const long long i = (long long)blockIdx.x * 256 + threadIdx.x;
  const float4* x4 = (const float4*)x;
  const float4 a = x4[2 * i];
  const float4 b = x4[2 * i + 1];
  uint4 o;
  o.x = (unsigned)f2bf(a.x) | ((unsigned)f2bf(a.y) << 16);
  o.y = (unsigned)f2bf(a.z) | ((unsigned)f2bf(a.w) << 16);
  o.z = (unsigned)f2bf(b.x) | ((unsigned)f2bf(b.y) << 16);
  o.w = (unsigned)f2bf(b.z) | ((unsigned)f2bf(b.w) << 16);
  ((uint4*)xb)[i] = o;
}

// ---------------------------------------------------------------------------
// Kernel 3: W_tot build (unchanged).
// ---------------------------------------------------------------------------
__global__ __launch_bounds__(256) void build_wtot_kernel(
    const float* __restrict__ Wb, const float* __restrict__ Am,
    const float* __restrict__ Bm, const float* __restrict__ DW,
    unsigned short* __restrict__ Wt, int j0) {
  const int jj = blockIdx.z;
  const int j = j0 + jj;
  const int i0 = blockIdx.x << 6;
  const int o0 = blockIdx.y << 6;
  __shared__ float Dl[64][67];
  __shared__ float Al[64][17];
  __shared__ float Bl[16][64];
  const int tid = threadIdx.x;

  const float* dwp = DW + ((size_t)j * DIM + i0) * DIM + o0;
#pragma unroll
  for (int q = 0; q < 4; ++q) {
    const int lin = q * 256 + tid;
    const int i = lin >> 4;
    const int o4 = (lin & 15) << 2;
    const float4 v = *(const float4*)(dwp + (size_t)i * DIM + o4);
    Dl[i][o4] = v.x; Dl[i][o4 + 1] = v.y; Dl[i][o4 + 2] = v.z; Dl[i][o4 + 3] = v.w;
  }
  {
    const int ai = tid >> 2, r4 = (tid & 3) << 2;
    const float4 v = *(const float4*)(Am + ((size_t)j * DIM + i0 + ai) * RANK + r4);
    Al[ai][r4] = v.x; Al[ai][r4 + 1] = v.y; Al[ai][r4 + 2] = v.z; Al[ai][r4 + 3] = v.w;
  }
  {
    const int br = tid >> 4, bo4 = (tid & 15) << 2;
    const float4 v = *(const float4*)(Bm + ((size_t)j * RANK + br) * DIM + o0 + bo4);
    Bl[br][bo4] = v.x; Bl[br][bo4 + 1] = v.y; Bl[br][bo4 + 2] = v.z; Bl[br][bo4 + 3] = v.w;
  }
  __syncthreads();

  const int oo = tid >> 5;
  const int i2 = (tid & 31) << 1;
#pragma unroll
  for (int p = 0; p < 8; ++p) {
    const int o = p * 8 + oo;
    const int og = o0 + o;
    const float2 wb = *(const float2*)(Wb + (size_t)og * DIM + i0 + i2);
    float s0 = wb.x + Dl[i2][o];
    float s1 = wb.y + Dl[i2 + 1][o];
#pragma unroll
    for (int r = 0; r < RANK; ++r) {
      const float bro = Bl[r][o];
      s0 += Al[i2][r] * bro;
      s1 += Al[i2 + 1][r] * bro;
    }
    const unsigned pk = (unsigned)f2bf(s0) | ((unsigned)f2bf(s1) << 16);
    *(unsigned*)(Wt + ((size_t)jj * DIM + og) * DIM + i0 + i2) = pk;
  }
}

// ---------------------------------------------------------------------------
// Kernel 4a: 8-phase 256x256 grouped GEMM (T2 swizzle, T4 counted vmcnt, T5).
// LDS: A: 4 groups (2buf x 2khalf) x 16KB at [0,64K); B same at [64K,128K).
// Group layout: 128 LDS-rows x 128B; LDS row r holds tile rows (2r,2r+1) x 32
// cols, chunk-swizzled c' = ((half<<2)|kg) ^ (r&7) on BOTH stage-src and read.
// ---------------------------------------------------------------------------
template <int BUF, int KK, int MQ, int VME, int SGRP, int SOP, int SKH, bool DOST>
__device__ __forceinline__ void do_phase(
    char* smem, int tid, int stile,
    const unsigned short* const* aB, const unsigned short* const* bB,
    const int* aoff, const int* boff, bf16x8* bfr, f32x4 (*acc)[4]) {
  const int grp = (BUF * 2 + KK) * 16384;
  if constexpr (MQ == 0) {
#pragma unroll
    for (int n = 0; n < 4; ++n)
      bfr[n] = *(const bf16x8*)(smem + 65536 + grp + boff[n]);
  }
  bf16x8 afr[4];
#pragma unroll
  for (int i = 0; i < 4; ++i)
    afr[i] = *(const bf16x8*)(smem + grp + aoff[MQ * 4 + i]);
  if constexpr (DOST) {
    const unsigned short* const* bs = SOP ? bB : aB;
#pragma unroll
    for (int q = 0; q < 2; ++q)
      gload_lds16(bs[q] + stile * 64 + SKH * 32,
                  smem + SOP * 65536 + SGRP * 16384 + q * 8192 + tid * 16);
  }
  __builtin_amdgcn_s_barrier();
  __builtin_amdgcn_s_setprio(1);
#pragma unroll
  for (int i = 0; i < 4; ++i)
#pragma unroll
    for (int n = 0; n < 4; ++n)
      acc[MQ * 4 + i][n] =
          __builtin_amdgcn_mfma_f32_16x16x32_bf16(afr[i], bfr[n], acc[MQ * 4 + i][n], 0, 0, 0);
  __builtin_amdgcn_s_setprio(0);
  vmwait<VME>();
  __builtin_amdgcn_s_barrier();
}

template <int SGRP, int SOP, int SKH>
__device__ __forceinline__ void do_stage(
    char* smem, int tid, int stile,
    const unsigned short* const* aB, const unsigned short* const* bB) {
  const unsigned short* const* bs = SOP ? bB : aB;
#pragma unroll
  for (int q = 0; q < 2; ++q)
    gload_lds16(bs[q] + stile * 64 + SKH * 32,
                smem + SOP * 65536 + SGRP * 16384 + q * 8192 + tid * 16);
}

__global__ __launch_bounds__(512, 2) void gemm8_kernel(
    const unsigned short* __restrict__ xb, const unsigned short* __restrict__ Wt,
    const int* __restrict__ perm, const int* __restrict__ meta,
    float* __restrict__ out, int j0, int npp) {
  extern __shared__ char smem[];
  const int ntiles = meta[17];
  const int flat = blockIdx.x;
  const int swz = (flat & 7) * (GRIDX2 / 8) + (flat >> 3);   // XCD-chunked (T1)
  const int mt = swz >> 4;
  const int nt = swz & 15;
  if (mt >= ntiles) return;
  const int adapter = meta[32 + 3 * mt];
  if (adapter < j0 || adapter >= j0 + npp) return;
  const int slot = adapter - j0;
  const int pbase = meta[32 + 3 * mt + 1];
  const int nbase = nt << 8;

  const int tid = threadIdx.x;
  const int lane = tid & 63;
  const int wave = tid >> 6;
  const int wr = wave >> 2, wc = wave & 3;       // 2M x 4N waves
  const int fr = lane & 15, kg = lane >> 4;      // fragment row / k-group

  // fragment ds_read byte offsets within a 16KB group (swizzled)
  int aoff[8], boff[4];
#pragma unroll
  for (int m = 0; m < 8; ++m) {
    const int row = wr * 128 + m * 16 + fr;
    const int r = row >> 1, hf = row & 1;
    const int c = ((hf << 2) | kg) ^ (r & 7);
    aoff[m] = r * 128 + c * 16;
  }
#pragma unroll
  for (int n = 0; n < 4; ++n) {
    const int row = wc * 64 + n * 16 + fr;
    const int r = row >> 1, hf = row & 1;
    const int c = ((hf << 2) | kg) ^ (r & 7);
    boff[n] = r * 128 + c * 16;
  }

  // stage source pointers (pre-swizzled global, linear LDS dest — rule 21)
  const unsigned short* aB[2];
  const unsigned short* bB[2];
#pragma unroll
  for (int q = 0; q < 2; ++q) {
    const int L = q * 512 + tid;
    const int r = L >> 3, c = L & 7;
    const int s = c ^ (r & 7);
    const int grow = 2 * r + (s >> 2);
    const int gk = (s & 3) << 3;
    int pr = perm[pbase + grow];
    if (pr < 0) pr = 0;
    aB[q] = xb + (size_t)pr * DIM + gk;
    bB[q] = Wt + ((size_t)slot * DIM + nbase + grow) * DIM + gk;
  }

  const f32x4 zero = {0.f, 0.f, 0.f, 0.f};
  f32x4 acc[8][4];
#pragma unroll
  for (int m = 0; m < 8; ++m)
#pragma unroll
    for (int n = 0; n < 4; ++n) acc[m][n] = zero;
  bf16x8 bfr[4];

  // prologue: tile0 (buf0) both k-halves, tile1 (buf1) k-half0
  do_stage<0, 0, 0>(smem, tid, 0, aB, bB);
  do_stage<0, 1, 0>(smem, tid, 0, aB, bB);
  do_stage<1, 0, 1>(smem, tid, 0, aB, bB);
  do_stage<1, 1, 1>(smem, tid, 0, aB, bB);
  do_stage<2, 0, 0>(smem, tid, 1, aB, bB);
  do_stage<2, 1, 0>(smem, tid, 1, aB, bB);
  vmwait<8>();
  __builtin_amdgcn_s_barrier();

  // main loop: iter computes tiles 2it (buf0), 2it+1 (buf1); stages +6 phases ahead
  for (int it = 0; it < 31; ++it) {
    const int t1 = 2 * it + 1, t2 = 2 * it + 2, t3 = 2 * it + 3;
    do_phase<0, 0, 0, 10, 3, 0, 1, true>(smem, tid, t1, aB, bB, aoff, boff, bfr, acc);
    do_phase<0, 0, 1, 8,  3, 1, 1, true>(smem, tid, t1, aB, bB, aoff, boff, bfr, acc);
    do_phase<0, 1, 0, 10, 0, 0, 0, true>(smem, tid, t2, aB, bB, aoff, boff, bfr, acc);
    do_phase<0, 1, 1, 8,  0, 1, 0, true>(smem, tid, t2, aB, bB, aoff, boff, bfr, acc);
    do_phase<1, 0, 0, 10, 1, 0, 1, true>(smem, tid, t2, aB, bB, aoff, boff, bfr, acc);
    do_phase<1, 0, 1, 8,  1, 1, 1, true>(smem, tid, t2, aB, bB, aoff, boff, bfr, acc);
    do_phase<1, 1, 0, 10, 2, 0, 0, true>(smem, tid, t3, aB, bB, aoff, boff, bfr, acc);
    do_phase<1, 1, 1, 8,  2, 1, 0, true>(smem, tid, t3, aB, bB, aoff, boff, bfr, acc);
  }
  // epilogue: tiles 62 (buf0), 63 (buf1); only tile63-k1 left to stage; drain
  do_phase<0, 0, 0, 10, 3, 0, 1, true >(smem, tid, 63, aB, bB, aoff, boff, bfr, acc);
  do_phase<0, 0, 1, 8,  3, 1, 1, true >(smem, tid, 63, aB, bB, aoff, boff, bfr, acc);
  do_phase<0, 1, 0, 8,  0, 0, 0, false>(smem, tid, 0,  aB, bB, aoff, boff, bfr, acc);
  do_phase<0, 1, 1, 4,  0, 0, 0, false>(smem, tid, 0,  aB, bB, aoff, boff, bfr, acc);
  do_phase<1, 0, 0, 4,  0, 0, 0, false>(smem, tid, 0,  aB, bB, aoff, boff, bfr, acc);
  do_phase<1, 0, 1, 0,  0, 0, 0, false>(smem, tid, 0,  aB, bB, aoff, boff, bfr, acc);
  do_phase<1, 1, 0, 0,  0, 0, 0, false>(smem, tid, 0,  aB, bB, aoff, boff, bfr, acc);
  do_phase<1, 1, 1, 0,  0, 0, 0, false>(smem, tid, 0,  aB, bB, aoff, boff, bfr, acc);

  // store: C/D map col=lane&15, row=(lane>>4)*4+reg
#pragma unroll
  for (int m = 0; m < 8; ++m) {
#pragma unroll
    for (int t = 0; t < 4; ++t) {
      const int rt = wr * 128 + m * 16 + kg * 4 + t;
      const int pr = perm[pbase + rt];
      if (pr < 0) continue;
      float* orow = out + (size_t)pr * DIM + nbase + wc * 64;
#pragma unroll
      for (int n = 0; n < 4; ++n) orow[n * 16 + fr] = acc[m][n][t];
    }
  }
}

// ---------------------------------------------------------------------------
// Kernel 4b: fallback 2-phase 128x128 grouped GEMM (proven-correct R2 kernel).
// ---------------------------------------------------------------------------
template <bool USE_XB>
__global__ __launch_bounds__(256) void gemm_kernel(
    const unsigned short* __restrict__ xb, const float* __restrict__ xf,
    const unsigned short* __restrict__ Wt,
    const int* __restrict__ perm, const int* __restrict__ meta,
    float* __restrict__ out, int j0, int npp) {
  const int ntiles = meta[17];
  const int mt = blockIdx.x;
  if (mt >= ntiles) return;
  const int adapter = meta[32 + 3 * mt];
  if (adapter < j0 || adapter >= j0 + npp) return;
  const int slot = adapter - j0;
  const int nt = blockIdx.y;
  const int pbase = meta[32 + 3 * mt + 1];
  const int nbase = nt << 7;

  __shared__ __align__(16) unsigned short As[BM1 * 64];
  __shared__ __align__(16) unsigned short Bs[BM1 * 64];

  const int tid = threadIdx.x;
  const int lane = tid & 63;
  const int wave = tid >> 6;

  const unsigned short* aSrcB[4];
  const float* aSrcF[4];
  const unsigned short* bSrc[4];
  unsigned short* aDst[4];
  unsigned short* bDst[4];
#pragma unroll
  for (int q = 0; q < 4; ++q) {
    const int c = wave * 4 + q;
    const int r = c * 8 + (lane >> 3);
    int pr = perm[pbase + r];
    if (pr < 0) pr = 0;
    if (USE_XB) aSrcB[q] = xb + (size_t)pr * DIM + (lane & 7) * 8;
    else        aSrcF[q] = xf + (size_t)pr * DIM + (lane & 7) * 8;
    bSrc[q] = Wt + ((size_t)slot * DIM + nbase + r) * DIM + (lane & 7) * 8;
    aDst[q] = As + c * 512;
    bDst[q] = Bs + c * 512;
  }

  const int wr = wave >> 1, wc = wave & 1;
  const int fr = lane & 15, kg = lane >> 4;

  const f32x4 zero = {0.f, 0.f, 0.f, 0.f};
  f32x4 acc[4][4];
#pragma unroll
  for (int m = 0; m < 4; ++m)
#pragma unroll
    for (int n = 0; n < 4; ++n) acc[m][n] = zero;

  for (int k0 = 0; k0 < DIM; k0 += 64) {
    if (USE_XB) {
#pragma unroll
      for (int q = 0; q < 4; ++q) gload_lds16(aSrcB[q] + k0, aDst[q]);
    } else {
#pragma unroll
      for (int q = 0; q < 4; ++q) {
        const float4 va = *(const float4*)(aSrcF[q] + k0);
        const float4 vb = *(const float4*)(aSrcF[q] + k0 + 4);
        union { bf16x8 v; unsigned short s[8]; } u;
        u.s[0] = f2bf(va.x); u.s[1] = f2bf(va.y); u.s[2] = f2bf(va.z); u.s[3] = f2bf(va.w);
        u.s[4] = f2bf(vb.x); u.s[5] = f2bf(vb.y); u.s[6] = f2bf(vb.z); u.s[7] = f2bf(vb.w);
        *(bf16x8*)(aDst[q] + lane * 8) = u.v;
      }
    }
#pragma unroll
    for (int q = 0; q < 4; ++q) gload_lds16(bSrc[q] + k0, bDst[q]);
    __syncthreads();
#pragma unroll
    for (int kk = 0; kk < 2; ++kk) {
      bf16x8 a[4], b[4];
#pragma unroll
      for (int m = 0; m < 4; ++m)
        a[m] = *(const bf16x8*)(&As[(wr * 64 + m * 16 + fr) * 64 + kk * 32 + kg * 8]);
#pragma unroll
      for (int n = 0; n < 4; ++n)
        b[n] = *(const bf16x8*)(&Bs[(wc * 64 + n * 16 + fr) * 64 + kk * 32 + kg * 8]);
#pragma unroll
      for (int m = 0; m < 4; ++m)
#pragma unroll
        for (int n = 0; n < 4; ++n)
          acc[m][n] = __builtin_amdgcn_mfma_f32_16x16x32_bf16(a[m], b[n], acc[m][n], 0, 0, 0);
    }
    __syncthreads();
  }

#pragma unroll
  for (int m = 0; m < 4; ++m) {
#pragma unroll
    for (int t = 0; t < 4; ++t) {
      const int rt = wr * 64 + m * 16 + kg * 4 + t;
      const int pr = perm[pbase + rt];
      if (pr < 0) continue;
      float* orow = out + (size_t)pr * DIM + nbase + wc * 64;
#pragma unroll
      for (int n = 0; n < 4; ++n) orow[n * 16 + fr] = acc[m][n][t];
    }
  }
}

// ---------------------------------------------------------------------------
extern "C" void kernel_launch(void* const* d_in, const int* in_sizes, int n_in,
                              void* d_out, int out_size, void* d_ws, size_t ws_size,
                              hipStream_t stream) {
  const float* x  = (const float*)d_in[0];
  const int* widx = (const int*)d_in[1];
  const float* Wb = (const float*)d_in[2];
  const float* Am = (const float*)d_in[3];
  const float* Bm = (const float*)d_in[4];
  const float* DW = (const float*)d_in[5];
  float* out = (float*)d_out;

  const size_t XB_BYTES = (size_t)T_TOKENS * DIM * 2;
  const size_t WT1_BYTES = (size_t)DIM * DIM * 2;
  const size_t PM_BYTES = 16384 * sizeof(int) + 4096;

  int npp = 0;
  bool use_xb = true;
  for (int cand = NADAPT; cand >= 1; cand >>= 1) {
    if (XB_BYTES + (size_t)cand * WT1_BYTES + PM_BYTES <= ws_size) { npp = cand; break; }
  }
  if (npp == 0) { npp = 1; use_xb = false; }

  // 128KB dynamic LDS for the 8-phase kernel; fall back if not grantable
  bool use8 = use_xb &&
      (hipFuncSetAttribute((const void*)gemm8_kernel,
                           hipFuncAttributeMaxDynamicSharedMemorySize, 131072) == hipSuccess);

  char* ws = (char*)d_ws;
  unsigned short* xb = (unsigned short*)ws;
  unsigned short* Wt = (unsigned short*)(ws + (use_xb ? XB_BYTES : 0));
  char* tail = (char*)Wt + (size_t)npp * WT1_BYTES;
  int* perm = (int*)tail;
  int* meta = (int*)(tail + 16384 * sizeof(int));

  prep_kernel<<<dim3(1), dim3(1024), 0, stream>>>(widx, perm, meta, use8 ? BM2 : BM1);
  if (use_xb)
    convert_x_kernel<<<dim3(T_TOKENS * DIM / (256 * 8)), dim3(256), 0, stream>>>(x, xb);

  const int passes = NADAPT / npp;
  for (int p = 0; p < passes; ++p) {
    const int j0 = p * npp;
    build_wtot_kernel<<<dim3(DIM / 64, DIM / 64, npp), dim3(256), 0, stream>>>(
        Wb, Am, Bm, DW, Wt, j0);
    if (use8)
      gemm8_kernel<<<dim3(GRIDX2), dim3(512), 131072, stream>>>(
          xb, Wt, perm, meta, out, j0, npp);
    else if (use_xb)
      gemm_kernel<true><<<dim3(MAXT1, DIM / 128), dim3(256), 0, stream>>>(
          xb, nullptr, Wt, perm, meta, out, j0, npp);
    else
      gemm_kernel<false><<<dim3(MAXT1, DIM / 128), dim3(256), 0, stream>>>(
          nullptr, x, Wt, perm, meta, out, j0, npp);
  }
}

// Round 4
// 702.955 us; speedup vs baseline: 1.4494x; 1.2593x over previous
//
#include <hip/hip_runtime.h>

// ---------------------------------------------------------------------------
// out = x @ W_base^T + x[t] @ (DeltaW[j] + A[j]B[j]);  T=8192, D=4096, J=8, R=16.
// W_tot[j][o][i] = Wb[o][i] + DW[j][i][o] + (A@B)[i][o]  (bf16, [N][K] layout),
// then ONE grouped GEMM.  GEMM = 256x256x64 8-phase schedule (T1+T2+T3+T4+T5).
// R4: build_wtot rewritten with 4x4 register tiling (was LDS-issue-bound).
// ---------------------------------------------------------------------------

#define T_TOKENS 8192
#define DIM 4096
#define NADAPT 8
#define RANK 16

// 8-phase GEMM geometry
#define BM2 256
#define BN2 256
#define MAXT2 40
#define GRIDX2 (MAXT2 * 16)   // 640, %8==0

// fallback 2-phase geometry
#define BM1 128
#define MAXT1 72

typedef __attribute__((ext_vector_type(8))) short bf16x8;
typedef __attribute__((ext_vector_type(4))) float f32x4;

__device__ __forceinline__ unsigned short f2bf(float f) {
  union { float f; unsigned u; } v; v.f = f;
  unsigned r = v.u + 0x7FFFu + ((v.u >> 16) & 1u);   // RNE
  return (unsigned short)(r >> 16);
}

__device__ __forceinline__ void gload_lds16(const void* g, void* l) {
  __builtin_amdgcn_global_load_lds(
      (const __attribute__((address_space(1))) void*)g,
      (__attribute__((address_space(3))) void*)l, 16, 0, 0);
}

template <int N> __device__ __forceinline__ void vmwait() {
  if constexpr (N == 0)       asm volatile("s_waitcnt vmcnt(0)" ::: "memory");
  else if constexpr (N == 4)  asm volatile("s_waitcnt vmcnt(4)" ::: "memory");
  else if constexpr (N == 8)  asm volatile("s_waitcnt vmcnt(8)" ::: "memory");
  else                        asm volatile("s_waitcnt vmcnt(10)" ::: "memory");
}

// ---------------------------------------------------------------------------
// Kernel 1: group tokens by adapter (stable compaction), tile descriptors.
// meta: [0..7]=counts, [8..16]=padded offsets, [17]=ntiles, [32+3t..]={adapter,pbase,rows}
// ---------------------------------------------------------------------------
__global__ void prep_kernel(const int* __restrict__ idx, int* __restrict__ perm,
                            int* __restrict__ meta, int padm) {
  __shared__ int s_cnt[NADAPT];
  __shared__ int s_padoff[NADAPT + 1];
  __shared__ int s_wsum[16];
  const int tid = threadIdx.x;
  const int lane = tid & 63;
  const int wave = tid >> 6;

  if (tid < NADAPT) s_cnt[tid] = 0;
  __syncthreads();
  for (int t = tid; t < T_TOKENS; t += 1024) atomicAdd(&s_cnt[idx[t]], 1);
  __syncthreads();

  if (tid == 0) {
    int off = 0, nt = 0;
    for (int j = 0; j < NADAPT; ++j) {
      meta[j] = s_cnt[j];
      s_padoff[j] = off;
      const int c = s_cnt[j];
      const int ntj = (c + padm - 1) / padm;
      for (int i = 0; i < ntj; ++i) {
        meta[32 + 3 * nt + 0] = j;
        meta[32 + 3 * nt + 1] = off + i * padm;
        meta[32 + 3 * nt + 2] = min(padm, c - i * padm);
        ++nt;
      }
      off += ntj * padm;
    }
    s_padoff[NADAPT] = off;
    meta[17] = nt;
    for (int j = 0; j <= NADAPT; ++j) meta[8 + j] = s_padoff[j];
  }
  __syncthreads();

  const int total_pad = s_padoff[NADAPT];
  for (int t = tid; t < total_pad; t += 1024) perm[t] = -1;
  __syncthreads();

  for (int j = 0; j < NADAPT; ++j) {
    int base = s_padoff[j];
    for (int c0 = 0; c0 < T_TOKENS; c0 += 1024) {
      const int t = c0 + tid;
      const int flag = (idx[t] == j) ? 1 : 0;
      const unsigned long long bal = __ballot(flag);
      const int wpos = __popcll(bal & ((1ULL << lane) - 1ULL));
      if (lane == 0) s_wsum[wave] = __popcll(bal);
      __syncthreads();
      int woff = 0, ctot = 0;
      for (int w = 0; w < 16; ++w) {
        const int v = s_wsum[w];
        if (w < wave) woff += v;
        ctot += v;
      }
      if (flag) perm[base + woff + wpos] = t;
      base += ctot;
      __syncthreads();
    }
  }
}

// ---------------------------------------------------------------------------
// Kernel 2: x fp32 -> bf16, vectorized.
// ---------------------------------------------------------------------------
__global__ void convert_x_kernel(const float* __restrict__ x,
                                 unsigned short* __restrict__ xb) {
  const long long i = (long long)blockIdx.x * 256 + threadIdx.x;
  const float4* x4 = (const float4*)x;
  const float4 a = x4[2 * i];
  const float4 b = x4[2 * i + 1];
  uint4 o;
  o.x = (unsigned)f2bf(a.x) | ((unsigned)f2bf(a.y) << 16);
  o.y = (unsigned)f2bf(a.z) | ((unsigned)f2bf(a.w) << 16);
  o.z = (unsigned)f2bf(b.x) | ((unsigned)f2bf(b.y) << 16);
  o.w = (unsigned)f2bf(b.z) | ((unsigned)f2bf(b.w) << 16);
  ((uint4*)xb)[i] = o;
}

// ---------------------------------------------------------------------------
// Kernel 3: W_tot[jj][o][i] = Wb[o][i] + DW[j][i][o] + sum_r A[i][r]B[r][o].
// 64x64 tile, 256 threads, 4x4 register tile per thread.
// Dl stored [o][i] (transposed at write) with quad-XOR swizzle (iq^=(o&15)):
// padding can't help here (b128 reads need stride%4==0, conflict-freedom wants
// odd), XOR keeps both transposing writes (~4-way) and b128 reads (~4-way) cheap.
// ---------------------------------------------------------------------------
__global__ __launch_bounds__(256) void build_wtot_kernel(
    const float* __restrict__ Wb, const float* __restrict__ Am,
    const float* __restrict__ Bm, const float* __restrict__ DW,
    unsigned short* __restrict__ Wt, int j0) {
  const int jj = blockIdx.z;
  const int j = j0 + jj;
  const int i0 = blockIdx.x << 6;
  const int o0 = blockIdx.y << 6;
  __shared__ float Dl[64 * 64];   // [o][i], quad-XOR swizzled
  __shared__ float Alt[16][68];   // [r][i]  (A transposed)
  __shared__ float Bl[16][68];    // [r][o]
  const int tid = threadIdx.x;

  // stage DW tile (transpose into swizzled Dl)
  const float* dwp = DW + ((size_t)j * DIM + i0) * DIM + o0;
#pragma unroll
  for (int q = 0; q < 4; ++q) {
    const int lin = q * 256 + tid;
    const int i = lin >> 4;
    const int o4 = (lin & 15) << 2;
    const float4 v = *(const float4*)(dwp + (size_t)i * DIM + o4);
    const int iq = i >> 2, ie = i & 3;
#pragma unroll
    for (int k = 0; k < 4; ++k) {
      const int o = o4 + k;
      Dl[o * 64 + (((iq ^ (o & 15)) << 2) | ie)] = ((const float*)&v)[k];
    }
  }
  // stage A transposed: Alt[r][i]
  {
    const int ai = tid >> 2, r4 = (tid & 3) << 2;
    const float4 v = *(const float4*)(Am + ((size_t)j * DIM + i0 + ai) * RANK + r4);
#pragma unroll
    for (int k = 0; k < 4; ++k) Alt[r4 + k][ai] = ((const float*)&v)[k];
  }
  // stage B: Bl[r][o]
  {
    const int br = tid >> 4, bo4 = (tid & 15) << 2;
    const float4 v = *(const float4*)(Bm + ((size_t)j * RANK + br) * DIM + o0 + bo4);
    *(float4*)&Bl[br][bo4] = v;
  }
  __syncthreads();

  const int to = (tid >> 4) << 2;   // o-offset 0..60
  const int ti = (tid & 15) << 2;   // i-offset 0..60
  float acc[4][4];                  // [m=o][e=i]

  // init: Wb + Dl
#pragma unroll
  for (int m = 0; m < 4; ++m) {
    const int o = to + m;
    const float4 w = *(const float4*)(Wb + (size_t)(o0 + o) * DIM + i0 + ti);
    const float4 d = *(const float4*)&Dl[o * 64 + (((ti >> 2) ^ (o & 15)) << 2)];
    acc[m][0] = w.x + d.x; acc[m][1] = w.y + d.y;
    acc[m][2] = w.z + d.z; acc[m][3] = w.w + d.w;
  }
  // rank-16 bilinear, 4x4 register tile: per r = 2 x b128 + 16 FMA
#pragma unroll
  for (int r = 0; r < RANK; ++r) {
    const float4 av = *(const float4*)&Alt[r][ti];
    const float4 bv = *(const float4*)&Bl[r][to];
#pragma unroll
    for (int m = 0; m < 4; ++m) {
      const float b = ((const float*)&bv)[m];
      acc[m][0] += b * av.x; acc[m][1] += b * av.y;
      acc[m][2] += b * av.z; acc[m][3] += b * av.w;
    }
  }
  // pack + store: 4 rows x 4 bf16 = 8B coalesced stores
#pragma unroll
  for (int m = 0; m < 4; ++m) {
    const int o = to + m;
    const unsigned lo = (unsigned)f2bf(acc[m][0]) | ((unsigned)f2bf(acc[m][1]) << 16);
    const unsigned hi = (unsigned)f2bf(acc[m][2]) | ((unsigned)f2bf(acc[m][3]) << 16);
    uint2 pk; pk.x = lo; pk.y = hi;
    *(uint2*)(Wt + ((size_t)jj * DIM + o0 + o) * DIM + i0 + ti) = pk;
  }
}

// ---------------------------------------------------------------------------
// Kernel 4a: 8-phase 256x256 grouped GEMM (T2 swizzle, T4 counted vmcnt, T5).
// LDS: A: 4 groups (2buf x 2khalf) x 16KB at [0,64K); B same at [64K,128K).
// Group layout: 128 LDS-rows x 128B; LDS row r holds tile rows (2r,2r+1) x 32
// cols, chunk-swizzled c' = ((half<<2)|kg) ^ (r&7) on BOTH stage-src and read.
// ---------------------------------------------------------------------------
template <int BUF, int KK, int MQ, int VME, int SGRP, int SOP, int SKH, bool DOST>
__device__ __forceinline__ void do_phase(
    char* smem, int tid, int stile,
    const unsigned short* const* aB, const unsigned short* const* bB,
    const int* aoff, const int* boff, bf16x8* bfr, f32x4 (*acc)[4]) {
  const int grp = (BUF * 2 + KK) * 16384;
  if constexpr (MQ == 0) {
#pragma unroll
    for (int n = 0; n < 4; ++n)
      bfr[n] = *(const bf16x8*)(smem + 65536 + grp + boff[n]);
  }
  bf16x8 afr[4];
#pragma unroll
  for (int i = 0; i < 4; ++i)
    afr[i] = *(const bf16x8*)(smem + grp + aoff[MQ * 4 + i]);
  if constexpr (DOST) {
    const unsigned short* const* bs = SOP ? bB : aB;
#pragma unroll
    for (int q = 0; q < 2; ++q)
      gload_lds16(bs[q] + stile * 64 + SKH * 32,
                  smem + SOP * 65536 + SGRP * 16384 + q * 8192 + tid * 16);
  }
  __builtin_amdgcn_s_barrier();
  __builtin_amdgcn_s_setprio(1);
#pragma unroll
  for (int i = 0; i < 4; ++i)
#pragma unroll
    for (int n = 0; n < 4; ++n)
      acc[MQ * 4 + i][n] =
          __builtin_amdgcn_mfma_f32_16x16x32_bf16(afr[i], bfr[n], acc[MQ * 4 + i][n], 0, 0, 0);
  __builtin_amdgcn_s_setprio(0);
  vmwait<VME>();
  __builtin_amdgcn_s_barrier();
}

template <int SGRP, int SOP, int SKH>
__device__ __forceinline__ void do_stage(
    char* smem, int tid, int stile,
    const unsigned short* const* aB, const unsigned short* const* bB) {
  const unsigned short* const* bs = SOP ? bB : aB;
#pragma unroll
  for (int q = 0; q < 2; ++q)
    gload_lds16(bs[q] + stile * 64 + SKH * 32,
                smem + SOP * 65536 + SGRP * 16384 + q * 8192 + tid * 16);
}

__global__ __launch_bounds__(512, 2) void gemm8_kernel(
    const unsigned short* __restrict__ xb, const unsigned short* __restrict__ Wt,
    const int* __restrict__ perm, const int* __restrict__ meta,
    float* __restrict__ out, int j0, int npp) {
  extern __shared__ char smem[];
  const int ntiles = meta[17];
  const int flat = blockIdx.x;
  const int swz = (flat & 7) * (GRIDX2 / 8) + (flat >> 3);   // XCD-chunked (T1)
  const int mt = swz >> 4;
  const int nt = swz & 15;
  if (mt >= ntiles) return;
  const int adapter = meta[32 + 3 * mt];
  if (adapter < j0 || adapter >= j0 + npp) return;
  const int slot = adapter - j0;
  const int pbase = meta[32 + 3 * mt + 1];
  const int nbase = nt << 8;

  const int tid = threadIdx.x;
  const int lane = tid & 63;
  const int wave = tid >> 6;
  const int wr = wave >> 2, wc = wave & 3;       // 2M x 4N waves
  const int fr = lane & 15, kg = lane >> 4;      // fragment row / k-group

  // fragment ds_read byte offsets within a 16KB group (swizzled)
  int aoff[8], boff[4];
#pragma unroll
  for (int m = 0; m < 8; ++m) {
    const int row = wr * 128 + m * 16 + fr;
    const int r = row >> 1, hf = row & 1;
    const int c = ((hf << 2) | kg) ^ (r & 7);
    aoff[m] = r * 128 + c * 16;
  }
#pragma unroll
  for (int n = 0; n < 4; ++n) {
    const int row = wc * 64 + n * 16 + fr;
    const int r = row >> 1, hf = row & 1;
    const int c = ((hf << 2) | kg) ^ (r & 7);
    boff[n] = r * 128 + c * 16;
  }

  // stage source pointers (pre-swizzled global, linear LDS dest — rule 21)
  const unsigned short* aB[2];
  const unsigned short* bB[2];
#pragma unroll
  for (int q = 0; q < 2; ++q) {
    const int L = q * 512 + tid;
    const int r = L >> 3, c = L & 7;
    const int s = c ^ (r & 7);
    const int grow = 2 * r + (s >> 2);
    const int gk = (s & 3) << 3;
    int pr = perm[pbase + grow];
    if (pr < 0) pr = 0;
    aB[q] = xb + (size_t)pr * DIM + gk;
    bB[q] = Wt + ((size_t)slot * DIM + nbase + grow) * DIM + gk;
  }

  const f32x4 zero = {0.f, 0.f, 0.f, 0.f};
  f32x4 acc[8][4];
#pragma unroll
  for (int m = 0; m < 8; ++m)
#pragma unroll
    for (int n = 0; n < 4; ++n) acc[m][n] = zero;
  bf16x8 bfr[4];

  // prologue: tile0 (buf0) both k-halves, tile1 (buf1) k-half0
  do_stage<0, 0, 0>(smem, tid, 0, aB, bB);
  do_stage<0, 1, 0>(smem, tid, 0, aB, bB);
  do_stage<1, 0, 1>(smem, tid, 0, aB, bB);
  do_stage<1, 1, 1>(smem, tid, 0, aB, bB);
  do_stage<2, 0, 0>(smem, tid, 1, aB, bB);
  do_stage<2, 1, 0>(smem, tid, 1, aB, bB);
  vmwait<8>();
  __builtin_amdgcn_s_barrier();

  // main loop: iter computes tiles 2it (buf0), 2it+1 (buf1); stages +6 phases ahead
  for (int it = 0; it < 31; ++it) {
    const int t1 = 2 * it + 1, t2 = 2 * it + 2, t3 = 2 * it + 3;
    do_phase<0, 0, 0, 10, 3, 0, 1, true>(smem, tid, t1, aB, bB, aoff, boff, bfr, acc);
    do_phase<0, 0, 1, 8,  3, 1, 1, true>(smem, tid, t1, aB, bB, aoff, boff, bfr, acc);
    do_phase<0, 1, 0, 10, 0, 0, 0, true>(smem, tid, t2, aB, bB, aoff, boff, bfr, acc);
    do_phase<0, 1, 1, 8,  0, 1, 0, true>(smem, tid, t2, aB, bB, aoff, boff, bfr, acc);
    do_phase<1, 0, 0, 10, 1, 0, 1, true>(smem, tid, t2, aB, bB, aoff, boff, bfr, acc);
    do_phase<1, 0, 1, 8,  1, 1, 1, true>(smem, tid, t2, aB, bB, aoff, boff, bfr, acc);
    do_phase<1, 1, 0, 10, 2, 0, 0, true>(smem, tid, t3, aB, bB, aoff, boff, bfr, acc);
    do_phase<1, 1, 1, 8,  2, 1, 0, true>(smem, tid, t3, aB, bB, aoff, boff, bfr, acc);
  }
  // epilogue: tiles 62 (buf0), 63 (buf1); only tile63-k1 left to stage; drain
  do_phase<0, 0, 0, 10, 3, 0, 1, true >(smem, tid, 63, aB, bB, aoff, boff, bfr, acc);
  do_phase<0, 0, 1, 8,  3, 1, 1, true >(smem, tid, 63, aB, bB, aoff, boff, bfr, acc);
  do_phase<0, 1, 0, 8,  0, 0, 0, false>(smem, tid, 0,  aB, bB, aoff, boff, bfr, acc);
  do_phase<0, 1, 1, 4,  0, 0, 0, false>(smem, tid, 0,  aB, bB, aoff, boff, bfr, acc);
  do_phase<1, 0, 0, 4,  0, 0, 0, false>(smem, tid, 0,  aB, bB, aoff, boff, bfr, acc);
  do_phase<1, 0, 1, 0,  0, 0, 0, false>(smem, tid, 0,  aB, bB, aoff, boff, bfr, acc);
  do_phase<1, 1, 0, 0,  0, 0, 0, false>(smem, tid, 0,  aB, bB, aoff, boff, bfr, acc);
  do_phase<1, 1, 1, 0,  0, 0, 0, false>(smem, tid, 0,  aB, bB, aoff, boff, bfr, acc);

  // store: C/D map col=lane&15, row=(lane>>4)*4+reg
#pragma unroll
  for (int m = 0; m < 8; ++m) {
#pragma unroll
    for (int t = 0; t < 4; ++t) {
      const int rt = wr * 128 + m * 16 + kg * 4 + t;
      const int pr = perm[pbase + rt];
      if (pr < 0) continue;
      float* orow = out + (size_t)pr * DIM + nbase + wc * 64;
#pragma unroll
      for (int n = 0; n < 4; ++n) orow[n * 16 + fr] = acc[m][n][t];
    }
  }
}

// ---------------------------------------------------------------------------
// Kernel 4b: fallback 2-phase 128x128 grouped GEMM (proven-correct R2 kernel).
// ---------------------------------------------------------------------------
template <bool USE_XB>
__global__ __launch_bounds__(256) void gemm_kernel(
    const unsigned short* __restrict__ xb, const float* __restrict__ xf,
    const unsigned short* __restrict__ Wt,
    const int* __restrict__ perm, const int* __restrict__ meta,
    float* __restrict__ out, int j0, int npp) {
  const int ntiles = meta[17];
  const int mt = blockIdx.x;
  if (mt >= ntiles) return;
  const int adapter = meta[32 + 3 * mt];
  if (adapter < j0 || adapter >= j0 + npp) return;
  const int slot = adapter - j0;
  const int nt = blockIdx.y;
  const int pbase = meta[32 + 3 * mt + 1];
  const int nbase = nt << 7;

  __shared__ __align__(16) unsigned short As[BM1 * 64];
  __shared__ __align__(16) unsigned short Bs[BM1 * 64];

  const int tid = threadIdx.x;
  const int lane = tid & 63;
  const int wave = tid >> 6;

  const unsigned short* aSrcB[4];
  const float* aSrcF[4];
  const unsigned short* bSrc[4];
  unsigned short* aDst[4];
  unsigned short* bDst[4];
#pragma unroll
  for (int q = 0; q < 4; ++q) {
    const int c = wave * 4 + q;
    const int r = c * 8 + (lane >> 3);
    int pr = perm[pbase + r];
    if (pr < 0) pr = 0;
    if (USE_XB) aSrcB[q] = xb + (size_t)pr * DIM + (lane & 7) * 8;
    else        aSrcF[q] = xf + (size_t)pr * DIM + (lane & 7) * 8;
    bSrc[q] = Wt + ((size_t)slot * DIM + nbase + r) * DIM + (lane & 7) * 8;
    aDst[q] = As + c * 512;
    bDst[q] = Bs + c * 512;
  }

  const int wr = wave >> 1, wc = wave & 1;
  const int fr = lane & 15, kg = lane >> 4;

  const f32x4 zero = {0.f, 0.f, 0.f, 0.f};
  f32x4 acc[4][4];
#pragma unroll
  for (int m = 0; m < 4; ++m)
#pragma unroll
    for (int n = 0; n < 4; ++n) acc[m][n] = zero;

  for (int k0 = 0; k0 < DIM; k0 += 64) {
    if (USE_XB) {
#pragma unroll
      for (int q = 0; q < 4; ++q) gload_lds16(aSrcB[q] + k0, aDst[q]);
    } else {
#pragma unroll
      for (int q = 0; q < 4; ++q) {
        const float4 va = *(const float4*)(aSrcF[q] + k0);
        const float4 vb = *(const float4*)(aSrcF[q] + k0 + 4);
        union { bf16x8 v; unsigned short s[8]; } u;
        u.s[0] = f2bf(va.x); u.s[1] = f2bf(va.y); u.s[2] = f2bf(va.z); u.s[3] = f2bf(va.w);
        u.s[4] = f2bf(vb.x); u.s[5] = f2bf(vb.y); u.s[6] = f2bf(vb.z); u.s[7] = f2bf(vb.w);
        *(bf16x8*)(aDst[q] + lane * 8) = u.v;
      }
    }
#pragma unroll
    for (int q = 0; q < 4; ++q) gload_lds16(bSrc[q] + k0, bDst[q]);
    __syncthreads();
#pragma unroll
    for (int kk = 0; kk < 2; ++kk) {
      bf16x8 a[4], b[4];
#pragma unroll
      for (int m = 0; m < 4; ++m)
        a[m] = *(const bf16x8*)(&As[(wr * 64 + m * 16 + fr) * 64 + kk * 32 + kg * 8]);
#pragma unroll
      for (int n = 0; n < 4; ++n)
        b[n] = *(const bf16x8*)(&Bs[(wc * 64 + n * 16 + fr) * 64 + kk * 32 + kg * 8]);
#pragma unroll
      for (int m = 0; m < 4; ++m)
#pragma unroll
        for (int n = 0; n < 4; ++n)
          acc[m][n] = __builtin_amdgcn_mfma_f32_16x16x32_bf16(a[m], b[n], acc[m][n], 0, 0, 0);
    }
    __syncthreads();
  }

#pragma unroll
  for (int m = 0; m < 4; ++m) {
#pragma unroll
    for (int t = 0; t < 4; ++t) {
      const int rt = wr * 64 + m * 16 + kg * 4 + t;
      const int pr = perm[pbase + rt];
      if (pr < 0) continue;
      float* orow = out + (size_t)pr * DIM + nbase + wc * 64;
#pragma unroll
      for (int n = 0; n < 4; ++n) orow[n * 16 + fr] = acc[m][n][t];
    }
  }
}

// ---------------------------------------------------------------------------
extern "C" void kernel_launch(void* const* d_in, const int* in_sizes, int n_in,
                              void* d_out, int out_size, void* d_ws, size_t ws_size,
                              hipStream_t stream) {
  const float* x  = (const float*)d_in[0];
  const int* widx = (const int*)d_in[1];
  const float* Wb = (const float*)d_in[2];
  const float* Am = (const float*)d_in[3];
  const float* Bm = (const float*)d_in[4];
  const float* DW = (const float*)d_in[5];
  float* out = (float*)d_out;

  const size_t XB_BYTES = (size_t)T_TOKENS * DIM * 2;
  const size_t WT1_BYTES = (size_t)DIM * DIM * 2;
  const size_t PM_BYTES = 16384 * sizeof(int) + 4096;

  int npp = 0;
  bool use_xb = true;
  for (int cand = NADAPT; cand >= 1; cand >>= 1) {
    if (XB_BYTES + (size_t)cand * WT1_BYTES + PM_BYTES <= ws_size) { npp = cand; break; }
  }
  if (npp == 0) { npp = 1; use_xb = false; }

  // 128KB dynamic LDS for the 8-phase kernel; fall back if not grantable
  bool use8 = use_xb &&
      (hipFuncSetAttribute((const void*)gemm8_kernel,
                           hipFuncAttributeMaxDynamicSharedMemorySize, 131072) == hipSuccess);

  char* ws = (char*)d_ws;
  unsigned short* xb = (unsigned short*)ws;
  unsigned short* Wt = (unsigned short*)(ws + (use_xb ? XB_BYTES : 0));
  char* tail = (char*)Wt + (size_t)npp * WT1_BYTES;
  int* perm = (int*)tail;
  int* meta = (int*)(tail + 16384 * sizeof(int));

  prep_kernel<<<dim3(1), dim3(1024), 0, stream>>>(widx, perm, meta, use8 ? BM2 : BM1);
  if (use_xb)
    convert_x_kernel<<<dim3(T_TOKENS * DIM / (256 * 8)), dim3(256), 0, stream>>>(x, xb);

  const int passes = NADAPT / npp;
  for (int p = 0; p < passes; ++p) {
    const int j0 = p * npp;
    build_wtot_kernel<<<dim3(DIM / 64, DIM / 64, npp), dim3(256), 0, stream>>>(
        Wb, Am, Bm, DW, Wt, j0);
    if (use8)
      gemm8_kernel<<<dim3(GRIDX2), dim3(512), 131072, stream>>>(
          xb, Wt, perm, meta, out, j0, npp);
    else if (use_xb)
      gemm_kernel<true><<<dim3(MAXT1, DIM / 128), dim3(256), 0, stream>>>(
          xb, nullptr, Wt, perm, meta, out, j0, npp);
    else
      gemm_kernel<false><<<dim3(MAXT1, DIM / 128), dim3(256), 0, stream>>>(
          nullptr, x, Wt, perm, meta, out, j0, npp);
  }
}